// Round 17
// baseline (635.429 us; speedup 1.0000x reference)
//
#include <hip/hip_runtime.h>
#include <hip/hip_fp16.h>

#define BQ 256
#define TQ 1024
#define FQ 37
#define UQ 64
#define G3 192
#define CH 8
#define NCK (TQ / CH)
#define CFD (CH * FQ)

typedef float v2f __attribute__((ext_vector_type(2)));

__device__ __forceinline__ float sigmoid_f(float x) {
    return 1.0f / (1.0f + __expf(-x));
}
__device__ __forceinline__ float tanh_f(float x) {
    return 1.0f - 2.0f / (__expf(2.0f * x) + 1.0f);
}

// =======================================================================
// Pass A (throughput): xp[b][k][g][j][tc] = (x@Wk + b0 + fold(b1 for z,r))
// fp16, packed so pass B reads one coalesced uint4 per (gate, chunk, lane).
// =======================================================================
__global__ __launch_bounds__(64) void xp_kernel(
    const float* __restrict__ values,   // [B,T,F]
    const float* __restrict__ Wk,       // [F,3U]
    const float* __restrict__ bias,     // [2,3U]
    __half*      __restrict__ xp)       // ws
{
    const int j   = threadIdx.x;        // gate-column lane (unit j)
    const int b   = blockIdx.x >> 4;
    const int seg = blockIdx.x & 15;    // 64-timestep segment

    float Kz[FQ], Kr[FQ], Kh[FQ];
#pragma unroll
    for (int f = 0; f < FQ; ++f) {
        Kz[f] = Wk[f * G3 + j];
        Kr[f] = Wk[f * G3 + 64 + j];
        Kh[f] = Wk[f * G3 + 128 + j];
    }
    const float bz  = bias[j] + bias[G3 + j];
    const float br  = bias[64 + j] + bias[G3 + 64 + j];
    const float bhx = bias[128 + j];

    const float* vb = values + (size_t)b * TQ * FQ;
    uint4* xw4 = (uint4*)(xp + (size_t)b * TQ * G3);

#pragma unroll 1
    for (int t8 = 0; t8 < 8; ++t8) {
        const int tb = seg * 64 + t8 * 8;
        unsigned int wz[4], wr_[4], wh[4];
        unsigned int tz = 0, tr = 0, th = 0;

#define ASTEP(S)                                                              \
        {                                                                     \
            const float* row = vb + (size_t)(tb + (S)) * FQ;                  \
            float az = bz, ar = br, ah = bhx;                                 \
            _Pragma("unroll")                                                 \
            for (int f = 0; f < FQ; ++f) {                                    \
                const float v = row[f];                                       \
                az += v * Kz[f]; ar += v * Kr[f]; ah += v * Kh[f];            \
            }                                                                 \
            const unsigned int uz = __half_as_ushort(__float2half(az));       \
            const unsigned int ur = __half_as_ushort(__float2half(ar));       \
            const unsigned int uh = __half_as_ushort(__float2half(ah));       \
            if ((S) & 1) {                                                    \
                wz[(S) >> 1] = tz | (uz << 16);                               \
                wr_[(S) >> 1] = tr | (ur << 16);                              \
                wh[(S) >> 1] = th | (uh << 16);                               \
            } else { tz = uz; tr = ur; th = uh; }                             \
        }
        ASTEP(0) ASTEP(1) ASTEP(2) ASTEP(3)
        ASTEP(4) ASTEP(5) ASTEP(6) ASTEP(7)
#undef ASTEP
        const size_t kk = (size_t)(seg * 8 + t8) * 3;
        uint4 oz; oz.x = wz[0];  oz.y = wz[1];  oz.z = wz[2];  oz.w = wz[3];
        uint4 orr; orr.x = wr_[0]; orr.y = wr_[1]; orr.z = wr_[2]; orr.w = wr_[3];
        uint4 oh; oh.x = wh[0];  oh.y = wh[1];  oh.z = wh[2];  oh.w = wh[3];
        xw4[(kk + 0) * 64 + j] = oz;
        xw4[(kk + 1) * 64 + j] = orr;
        xw4[(kk + 2) * 64 + j] = oh;
    }
}

// =======================================================================
// Pass B (latency): ONE wave per batch. Single branch -> allocator gets the
// whole 256-arch-VGPR budget for the 192 weights (R9-R16: a producer branch
// froze VGPR_Count at 148 and the weights never became arch-resident).
// No barriers (1 wave). xp via coalesced uint4 prefetched 1 chunk ahead.
// h-broadcast: LDS uniform b128 (R15's proven +10%). Head dbuf'd, hidden.
// =======================================================================
__global__ __launch_bounds__(64)
__attribute__((amdgpu_waves_per_eu(1, 1)))
void gru_1w(const int*    __restrict__ lengths,  // [B]
            const float*  __restrict__ Wr,       // [U,3U]
            const float*  __restrict__ bias,     // [2,3U]
            const float*  __restrict__ dw,       // [U]
            const float*  __restrict__ db,       // [1]
            const __half* __restrict__ xp,       // ws
            float*        __restrict__ out)      // [B,T]
{
    const int j = threadIdx.x;
    const int b = blockIdx.x;

    __shared__ __align__(16) float s_h[2][CH][72];   // h ring (dbuf for head)
    __shared__ float s_dw[UQ];

    v2f Pz[32], Pr[32], Ph[32];          // weight pairs over u
#pragma unroll
    for (int i = 0; i < 32; ++i) {
        v2f tz, tr, th;
        tz.x = Wr[(2 * i) * G3 + j];        tz.y = Wr[(2 * i + 1) * G3 + j];
        tr.x = Wr[(2 * i) * G3 + 64 + j];   tr.y = Wr[(2 * i + 1) * G3 + 64 + j];
        th.x = Wr[(2 * i) * G3 + 128 + j];  th.y = Wr[(2 * i + 1) * G3 + 128 + j];
        Pz[i] = tz; Pr[i] = tr; Ph[i] = th;
    }
    const float bh  = bias[G3 + 128 + j];
    const int   len = lengths[b];
    const float dbv = db[0];
    s_dw[j] = dw[j];
    s_h[1][7][j] = 0.0f;                 // h0 = 0 (prev slot of chunk 0)

    const uint4* xb = (const uint4*)(xp + (size_t)b * TQ * G3);
    float* ob = out + (size_t)b * TQ;

    // prologue: chunk0 resident, chunk1 in flight
    uint4 xqz = xb[0 * 64 + j], xqr = xb[1 * 64 + j], xqh = xb[2 * 64 + j];
    uint4 nqz = xb[3 * 64 + j], nqr = xb[4 * 64 + j], nqh = xb[5 * 64 + j];

    float h = 0.0f;
    const float* prow = &s_h[1][7][0];

#define XTRACT(DST, Q, TC)                                                    \
    {                                                                         \
        unsigned int _w = ((TC) >> 1) == 0 ? (Q).x : ((TC) >> 1) == 1 ?       \
            (Q).y : ((TC) >> 1) == 2 ? (Q).z : (Q).w;                         \
        if ((TC) & 1) _w >>= 16;                                              \
        DST = __half2float(__ushort_as_half((unsigned short)_w));             \
    }
#define PKF(ACC, WP, HV) asm("v_pk_fma_f32 %0, %1, %2, %0"                    \
        : "+v"(ACC) : "v"(WP), "v"(HV));
#define CONS(QI, HA)                                                          \
    { const v2f* hv = (const v2f*)&(HA);                                      \
      PKF(azp, Pz[2 * (QI)],     hv[0]) PKF(arp, Pr[2 * (QI)],     hv[0])     \
      PKF(ahp, Ph[2 * (QI)],     hv[0]) PKF(azp, Pz[2 * (QI) + 1], hv[1])     \
      PKF(arp, Pr[2 * (QI) + 1], hv[1]) PKF(ahp, Ph[2 * (QI) + 1], hv[1]) }

#define STEP(TC)                                                              \
    {                                                                         \
        float xz, xr, xh;                                                     \
        XTRACT(xz, xqz, TC) XTRACT(xr, xqr, TC) XTRACT(xh, xqh, TC)           \
        const float4* hp4 = (const float4*)prow;                              \
        v2f azp; azp.x = 0.f; azp.y = 0.f;                                    \
        v2f arp; arp.x = 0.f; arp.y = 0.f;                                    \
        v2f ahp; ahp.x = 0.f; ahp.y = 0.f;                                    \
        float4 ha0 = hp4[0], ha1 = hp4[1], ha2 = hp4[2], ha3 = hp4[3];        \
        CONS(0, ha0)  ha0 = hp4[4];                                           \
        CONS(1, ha1)  ha1 = hp4[5];                                           \
        CONS(2, ha2)  ha2 = hp4[6];                                           \
        CONS(3, ha3)  ha3 = hp4[7];                                           \
        CONS(4, ha0)  ha0 = hp4[8];                                           \
        CONS(5, ha1)  ha1 = hp4[9];                                           \
        CONS(6, ha2)  ha2 = hp4[10];                                          \
        CONS(7, ha3)  ha3 = hp4[11];                                          \
        CONS(8, ha0)  ha0 = hp4[12];                                          \
        CONS(9, ha1)  ha1 = hp4[13];                                          \
        CONS(10, ha2) ha2 = hp4[14];                                          \
        CONS(11, ha3) ha3 = hp4[15];                                          \
        CONS(12, ha0) CONS(13, ha1) CONS(14, ha2) CONS(15, ha3)               \
        const float az = azp.x + azp.y;                                       \
        const float ar = arp.x + arp.y;                                       \
        const float ah = ahp.x + ahp.y;                                       \
        const float z  = sigmoid_f(xz + az);                                  \
        const float r  = sigmoid_f(xr + ar);                                  \
        const float cc = tanh_f(xh + r * (bh + ah));                          \
        const float hn = z * h + (1.0f - z) * cc;                             \
        h = ((k * CH + (TC)) < len) ? hn : h;                                 \
        s_h[cb][TC][j] = h;                                                   \
        prow = &s_h[cb][TC][0];                                               \
    }

#define HEAD(HB, TB)                                                          \
    {                                                                         \
        const int e = j & 7, s = j >> 3;                                      \
        const float4* hr = (const float4*)&s_h[HB][s][e * 8];                 \
        float4 h0 = hr[0], h1 = hr[1];                                        \
        const float4* dr = (const float4*)&s_dw[e * 8];                       \
        float4 d0 = dr[0], d1 = dr[1];                                        \
        float pp = h0.x * d0.x + h0.y * d0.y + h0.z * d0.z + h0.w * d0.w      \
                 + h1.x * d1.x + h1.y * d1.y + h1.z * d1.z + h1.w * d1.w;     \
        pp += __shfl_xor(pp, 1, 64);                                          \
        pp += __shfl_xor(pp, 2, 64);                                          \
        pp += __shfl_xor(pp, 4, 64);                                          \
        if (e == 0) ob[(TB) + s] = sigmoid_f(pp + dbv);                       \
    }

#pragma unroll 1
    for (int k = 0; k < NCK; ++k) {
        const int cb = k & 1;
        if (k > 0) HEAD(cb ^ 1, (k - 1) * CH)   // prev chunk; latency hides
        STEP(0) STEP(1) STEP(2) STEP(3)
        STEP(4) STEP(5) STEP(6) STEP(7)
        if (k + 1 < NCK) {
            xqz = nqz; xqr = nqr; xqh = nqh;     // compiler inserts vmcnt wait
            if (k + 2 < NCK) {
                const int kb = (k + 2) * 3;
                nqz = xb[(kb + 0) * 64 + j];
                nqr = xb[(kb + 1) * 64 + j];
                nqh = xb[(kb + 2) * 64 + j];
            }
        }
    }
    HEAD((NCK - 1) & 1, (NCK - 1) * CH)

#undef XTRACT
#undef PKF
#undef CONS
#undef STEP
#undef HEAD
}

// =======================================================================
// Fallback (ws too small): R15's 2-wave kernel, proven 486us / absmax 0.
// =======================================================================
__global__ __launch_bounds__(128)
__attribute__((amdgpu_waves_per_eu(1, 1)))
void gru_ldsb(const float* __restrict__ values, const int* __restrict__ lengths,
              const float* __restrict__ Wk, const float* __restrict__ Wr,
              const float* __restrict__ bias, const float* __restrict__ dw,
              const float* __restrict__ db, float* __restrict__ out)
{
    const int tid = threadIdx.x;
    const int j   = tid & 63;
    const int w   = tid >> 6;
    const int b   = blockIdx.x;
    __shared__ __align__(16) float s_v[2][CH][40];
    __shared__ float s_xp[2][CH][G3];
    __shared__ __align__(16) float s_h8[2][CH][76];
    const float* vbp = values + (size_t)b * TQ * FQ;
    float* ob = out + (size_t)b * TQ;
    if (w == 0) {
        v2f Pz[32], Pr[32], Ph[32];
#pragma unroll
        for (int i = 0; i < 32; ++i) {
            v2f tz, tr, th;
            tz.x = Wr[(2 * i) * G3 + j];        tz.y = Wr[(2 * i + 1) * G3 + j];
            tr.x = Wr[(2 * i) * G3 + 64 + j];   tr.y = Wr[(2 * i + 1) * G3 + 64 + j];
            th.x = Wr[(2 * i) * G3 + 128 + j];  th.y = Wr[(2 * i + 1) * G3 + 128 + j];
            Pz[i] = tz; Pr[i] = tr; Ph[i] = th;
        }
        const float bh = bias[G3 + 128 + j];
        const int len = lengths[b];
        s_h8[1][7][j] = 0.0f;
        asm volatile("s_waitcnt lgkmcnt(0)" ::: "memory");
        __builtin_amdgcn_s_barrier();
        float h = 0.0f;
        const float* hprev = &s_h8[1][7][0];
#pragma unroll 1
        for (int k = 0; k < NCK; ++k) {
            const int pb = k & 1;
            const int tbase = k * CH;
#pragma unroll 1
            for (int tc = 0; tc < CH; ++tc) {
                const float xz = s_xp[pb][tc][j];
                const float xr = s_xp[pb][tc][64 + j];
                const float xh = s_xp[pb][tc][128 + j];
                const float4* hp4 = (const float4*)hprev;
                v2f azp; azp.x = 0.f; azp.y = 0.f;
                v2f arp; arp.x = 0.f; arp.y = 0.f;
                v2f ahp; ahp.x = 0.f; ahp.y = 0.f;
#define PKB(ACC, WP, HV) asm("v_pk_fma_f32 %0, %1, %2, %0" \
        : "+v"(ACC) : "v"(WP), "v"(HV));
                float4 ha[8];
#pragma unroll
                for (int q = 0; q < 8; ++q) ha[q] = hp4[q];
#pragma unroll
                for (int q = 0; q < 8; ++q) {
                    const v2f* hv = (const v2f*)&ha[q];
                    PKB(azp, Pz[2 * q],     hv[0])
                    PKB(arp, Pr[2 * q],     hv[0])
                    PKB(ahp, Ph[2 * q],     hv[0])
                    PKB(azp, Pz[2 * q + 1], hv[1])
                    PKB(arp, Pr[2 * q + 1], hv[1])
                    PKB(ahp, Ph[2 * q + 1], hv[1])
                    ha[q] = hp4[8 + q];
                }
#pragma unroll
                for (int q = 0; q < 8; ++q) {
                    const v2f* hv = (const v2f*)&ha[q];
                    PKB(azp, Pz[16 + 2 * q],     hv[0])
                    PKB(arp, Pr[16 + 2 * q],     hv[0])
                    PKB(ahp, Ph[16 + 2 * q],     hv[0])
                    PKB(azp, Pz[16 + 2 * q + 1], hv[1])
                    PKB(arp, Pr[16 + 2 * q + 1], hv[1])
                    PKB(ahp, Ph[16 + 2 * q + 1], hv[1])
                }
#undef PKB
                const float az = azp.x + azp.y;
                const float ar = arp.x + arp.y;
                const float ah = ahp.x + ahp.y;
                const float z  = sigmoid_f(xz + az);
                const float r  = sigmoid_f(xr + ar);
                const float cc = tanh_f(xh + r * (bh + ah));
                const float hn = z * h + (1.0f - z) * cc;
                h = ((tbase + tc) < len) ? hn : h;
                s_h8[pb][tc][j] = h;
                asm volatile("s_waitcnt lgkmcnt(0)" ::: "memory");
                hprev = &s_h8[pb][tc][0];
            }
            __builtin_amdgcn_s_barrier();
        }
    } else {
        float Kz[FQ], Kr[FQ], Kh[FQ];
#pragma unroll
        for (int f = 0; f < FQ; ++f) {
            Kz[f] = Wk[f * G3 + j];
            Kr[f] = Wk[f * G3 + 64 + j];
            Kh[f] = Wk[f * G3 + 128 + j];
        }
        const float bz  = bias[j] + bias[G3 + j];
        const float br  = bias[64 + j] + bias[G3 + 64 + j];
        const float bhx = bias[128 + j];
        const float dbv = db[0];
        float dwv[8];
#pragma unroll
        for (int i = 0; i < 8; ++i) dwv[i] = dw[(j & 7) * 8 + i];
        int rq[5], cq[5];
        bool act[5];
        float stg[5];
#pragma unroll
        for (int q = 0; q < 5; ++q) {
            const int idx = j + 64 * q;
            act[q] = idx < CFD;
            rq[q] = idx / FQ;
            cq[q] = idx - rq[q] * FQ;
            stg[q] = 0.0f;
        }
#define STAGE_LOAD(CK)                                                        \
        _Pragma("unroll")                                                     \
        for (int q = 0; q < 5; ++q)                                           \
            if (act[q]) stg[q] = vbp[(size_t)(CK) * CFD + j + 64 * q];
#define STAGE_WRITE(SB)                                                       \
        _Pragma("unroll")                                                     \
        for (int q = 0; q < 5; ++q)                                           \
            if (act[q]) s_v[SB][rq[q]][cq[q]] = stg[q];
#define XF(VAL, I) { az += (VAL) * Kz[I]; ar += (VAL) * Kr[I]; ah += (VAL) * Kh[I]; }
#define XPROW(BB)                                                             \
    _Pragma("unroll 1")                                                       \
    for (int row = 0; row < CH; ++row) {                                      \
        const float4* vr = (const float4*)&s_v[BB][row][0];                   \
        float az = bz, ar = br, ah = bhx;                                     \
        { float4 v0 = vr[0], v1 = vr[1], v2 = vr[2];                          \
          XF(v0.x, 0)  XF(v0.y, 1)  XF(v0.z, 2)  XF(v0.w, 3)                  \
          XF(v1.x, 4)  XF(v1.y, 5)  XF(v1.z, 6)  XF(v1.w, 7)                  \
          XF(v2.x, 8)  XF(v2.y, 9)  XF(v2.z, 10) XF(v2.w, 11) }               \
        { float4 v3 = vr[3], v4 = vr[4], v5 = vr[5];                          \
          XF(v3.x, 12) XF(v3.y, 13) XF(v3.z, 14) XF(v3.w, 15)                 \
          XF(v4.x, 16) XF(v4.y, 17) XF(v4.z, 18) XF(v4.w, 19)                 \
          XF(v5.x, 20) XF(v5.y, 21) XF(v5.z, 22) XF(v5.w, 23) }               \
        { float4 v6 = vr[6], v7 = vr[7], v8 = vr[8];                          \
          float f36 = s_v[BB][row][36];                                       \
          XF(v6.x, 24) XF(v6.y, 25) XF(v6.z, 26) XF(v6.w, 27)                 \
          XF(v7.x, 28) XF(v7.y, 29) XF(v7.z, 30) XF(v7.w, 31)                 \
          XF(v8.x, 32) XF(v8.y, 33) XF(v8.z, 34) XF(v8.w, 35)                 \
          XF(f36, 36) }                                                       \
        s_xp[BB][row][j]       = az;                                          \
        s_xp[BB][row][64 + j]  = ar;                                          \
        s_xp[BB][row][128 + j] = ah;                                          \
    }
#define HEADF(HB, TB)                                                         \
    {                                                                         \
        const int e = j & 7, s = j >> 3;                                      \
        const float4* hr = (const float4*)&s_h8[HB][s][e * 8];                \
        float4 ha = hr[0], hc = hr[1];                                        \
        float pp = ha.x * dwv[0] + ha.y * dwv[1] + ha.z * dwv[2]              \
                 + ha.w * dwv[3] + hc.x * dwv[4] + hc.y * dwv[5]              \
                 + hc.z * dwv[6] + hc.w * dwv[7];                             \
        pp += __shfl_xor(pp, 1, 64);                                          \
        pp += __shfl_xor(pp, 2, 64);                                          \
        pp += __shfl_xor(pp, 4, 64);                                          \
        if (e == 0) ob[(TB) + s] = sigmoid_f(pp + dbv);                       \
    }
        STAGE_LOAD(0)
        asm volatile("s_waitcnt vmcnt(0)" ::: "memory");
        STAGE_WRITE(0)
        STAGE_LOAD(1)
        asm volatile("s_waitcnt vmcnt(0)" ::: "memory");
        STAGE_WRITE(1)
        STAGE_LOAD(2)
        asm volatile("s_waitcnt lgkmcnt(0)" ::: "memory");
        XPROW(0)
        asm volatile("s_waitcnt lgkmcnt(0)" ::: "memory");
        __builtin_amdgcn_s_barrier();
#pragma unroll 1
        for (int k = 0; k < NCK; ++k) {
            const int pb = k & 1, nb = pb ^ 1;
            if (k > 0) HEADF(nb, (k - 1) * CH)
            if (k + 2 < NCK) {
                asm volatile("s_waitcnt vmcnt(0)" ::: "memory");
                STAGE_WRITE(pb)
                if (k + 3 < NCK) STAGE_LOAD(k + 3)
            }
            if (k + 1 < NCK) XPROW(nb)
            asm volatile("s_waitcnt lgkmcnt(0)" ::: "memory");
            __builtin_amdgcn_s_barrier();
        }
        HEADF((NCK - 1) & 1, (NCK - 1) * CH)
#undef STAGE_LOAD
#undef STAGE_WRITE
#undef XF
#undef XPROW
#undef HEADF
    }
}

extern "C" void kernel_launch(void* const* d_in, const int* in_sizes, int n_in,
                              void* d_out, int out_size, void* d_ws, size_t ws_size,
                              hipStream_t stream) {
    const float* values  = (const float*)d_in[2];
    const int*   lengths = (const int*)  d_in[4];
    const float* Wk      = (const float*)d_in[5];
    const float* Wr      = (const float*)d_in[6];
    const float* bias    = (const float*)d_in[7];
    const float* dw      = (const float*)d_in[8];
    const float* db      = (const float*)d_in[9];
    float* out = (float*)d_out;

    const size_t need = (size_t)BQ * TQ * G3 * sizeof(__half);  // 100.66 MB
    if (ws_size >= need) {
        __half* xp = (__half*)d_ws;
        xp_kernel<<<dim3(BQ * 16), dim3(64), 0, stream>>>(values, Wk, bias, xp);
        gru_1w<<<dim3(BQ), dim3(64), 0, stream>>>(
            lengths, Wr, bias, dw, db, xp, out);
    } else {
        gru_ldsb<<<dim3(BQ), dim3(128), 0, stream>>>(
            values, lengths, Wk, Wr, bias, dw, db, out);
    }
}

// Round 18
// 545.237 us; speedup vs baseline: 1.1654x; 1.1654x over previous
//
#include <hip/hip_runtime.h>
#include <hip/hip_fp16.h>

#define BQ 256
#define TQ 1024
#define FQ 37
#define UQ 64
#define G3 192
#define CH 8
#define NCK (TQ / CH)
#define CFD (CH * FQ)

typedef float v2f __attribute__((ext_vector_type(2)));
typedef _Float16 h2v __attribute__((ext_vector_type(2)));

__device__ __forceinline__ float sigmoid_f(float x) {
    return 1.0f / (1.0f + __expf(-x));
}
__device__ __forceinline__ float tanh_f(float x) {
    return 1.0f - 2.0f / (__expf(2.0f * x) + 1.0f);
}
__device__ __forceinline__ float fdot2f(h2v a, h2v b, float c) {
#if __has_builtin(__builtin_amdgcn_fdot2)
    return __builtin_amdgcn_fdot2(a, b, c, false);
#else
    float d;
    asm("v_dot2_f32_f16 %0, %1, %2, %3" : "=v"(d) : "v"(a), "v"(b), "v"(c));
    return d;
#endif
}
__device__ __forceinline__ h2v u2h(unsigned int u) {
    union { unsigned int x; h2v h; } v; v.x = u; return v.h;
}

// =======================================================================
// Pass A: xp (fp16, same layout as R17) — now with LDS-staged values
// (R17 read values via 2368 serialized uniform global loads -> 137us).
// One wave per (b, 64-step segment); stage 64x37 f32 in LDS coalesced.
// =======================================================================
__global__ __launch_bounds__(64) void xp_kernel(
    const float* __restrict__ values,   // [B,T,F]
    const float* __restrict__ Wk,       // [F,3U]
    const float* __restrict__ bias,     // [2,3U]
    __half*      __restrict__ xp)       // ws
{
    const int j   = threadIdx.x;
    const int b   = blockIdx.x >> 4;
    const int seg = blockIdx.x & 15;

    __shared__ __align__(16) float s_val[64][40];

    float Kz[FQ], Kr[FQ], Kh[FQ];
#pragma unroll
    for (int f = 0; f < FQ; ++f) {
        Kz[f] = Wk[f * G3 + j];
        Kr[f] = Wk[f * G3 + 64 + j];
        Kh[f] = Wk[f * G3 + 128 + j];
    }
    const float bz  = bias[j] + bias[G3 + j];
    const float br  = bias[64 + j] + bias[G3 + 64 + j];
    const float bhx = bias[128 + j];

    const float* vb = values + (size_t)b * TQ * FQ + (size_t)seg * 64 * FQ;
    uint4* xw4 = (uint4*)(xp + (size_t)b * TQ * G3);

    // stage the segment's values (64x37) coalesced; single wave -> lgkmcnt only
#pragma unroll 1
    for (int i = 0; i < 37; ++i) {
        const int idx = i * 64 + j;
        const int r = idx / FQ, c = idx - r * FQ;
        s_val[r][c] = vb[idx];
    }
    asm volatile("s_waitcnt vmcnt(0) lgkmcnt(0)" ::: "memory");

#pragma unroll 1
    for (int t8 = 0; t8 < 8; ++t8) {
        unsigned int wz[4], wr_[4], wh[4];
        unsigned int tz = 0, tr = 0, th = 0;

#define ASTEP(S)                                                              \
        {                                                                     \
            const float* row = &s_val[t8 * 8 + (S)][0];                       \
            float az = bz, ar = br, ah = bhx;                                 \
            _Pragma("unroll")                                                 \
            for (int f = 0; f < FQ; ++f) {                                    \
                const float v = row[f];                                       \
                az += v * Kz[f]; ar += v * Kr[f]; ah += v * Kh[f];            \
            }                                                                 \
            const unsigned int uz = __half_as_ushort(__float2half(az));       \
            const unsigned int ur = __half_as_ushort(__float2half(ar));       \
            const unsigned int uh = __half_as_ushort(__float2half(ah));       \
            if ((S) & 1) {                                                    \
                wz[(S) >> 1] = tz | (uz << 16);                               \
                wr_[(S) >> 1] = tr | (ur << 16);                              \
                wh[(S) >> 1] = th | (uh << 16);                               \
            } else { tz = uz; tr = ur; th = uh; }                             \
        }
        ASTEP(0) ASTEP(1) ASTEP(2) ASTEP(3)
        ASTEP(4) ASTEP(5) ASTEP(6) ASTEP(7)
#undef ASTEP
        const size_t kk = (size_t)(seg * 8 + t8) * 3;
        uint4 oz; oz.x = wz[0];  oz.y = wz[1];  oz.z = wz[2];  oz.w = wz[3];
        uint4 orr; orr.x = wr_[0]; orr.y = wr_[1]; orr.z = wr_[2]; orr.w = wr_[3];
        uint4 oh; oh.x = wh[0];  oh.y = wh[1];  oh.z = wh[2];  oh.w = wh[3];
        xw4[(kk + 0) * 64 + j] = oz;
        xw4[(kk + 1) * 64 + j] = orr;
        xw4[(kk + 2) * 64 + j] = oh;
    }
}

// =======================================================================
// Pass B: ONE wave per batch; fp16 weights + fp16 h broadcast + fdot2.
// Live set ~145 VGPR << 256 arch cap: R9-R17 showed demand near/over 256
// gets split into AGPRs with per-use v_accvgpr copies in the loop (~500cy
// of the 1170cy step). fp16 halves both the weight file (96 regs) and the
// broadcast reads (8 uniform b128). f32 accumulate via v_dot2_f32_f16.
// =======================================================================
__global__ __launch_bounds__(64)
__attribute__((amdgpu_waves_per_eu(1, 1)))
void gru_1w(const int*    __restrict__ lengths,  // [B]
            const float*  __restrict__ Wr,       // [U,3U]
            const float*  __restrict__ bias,     // [2,3U]
            const float*  __restrict__ dw,       // [U]
            const float*  __restrict__ db,       // [1]
            const __half* __restrict__ xp,       // ws
            float*        __restrict__ out)      // [B,T]
{
    const int j = threadIdx.x;
    const int b = blockIdx.x;

    __shared__ __align__(16) _Float16 s_h16[2][CH][72];  // h ring, fp16 (144B rows)
    __shared__ float s_dw[UQ];

    h2v Pz[32], Pr[32], Ph[32];          // fp16 weight pairs over u (96 VGPRs)
#pragma unroll
    for (int i = 0; i < 32; ++i) {
        h2v tz, tr, th;
        tz.x = (_Float16)Wr[(2 * i) * G3 + j];
        tz.y = (_Float16)Wr[(2 * i + 1) * G3 + j];
        tr.x = (_Float16)Wr[(2 * i) * G3 + 64 + j];
        tr.y = (_Float16)Wr[(2 * i + 1) * G3 + 64 + j];
        th.x = (_Float16)Wr[(2 * i) * G3 + 128 + j];
        th.y = (_Float16)Wr[(2 * i + 1) * G3 + 128 + j];
        Pz[i] = tz; Pr[i] = tr; Ph[i] = th;
    }
    const float bh  = bias[G3 + 128 + j];
    const int   len = lengths[b];
    const float dbv = db[0];
    s_dw[j] = dw[j];
    s_h16[1][CH - 1][j] = (_Float16)0.0f;    // h0 = 0

    const uint4* xb = (const uint4*)(xp + (size_t)b * TQ * G3);
    float* ob = out + (size_t)b * TQ;

    // prologue: chunk0 resident, chunk1 in flight
    uint4 xqz = xb[0 * 64 + j], xqr = xb[1 * 64 + j], xqh = xb[2 * 64 + j];
    uint4 nqz = xb[3 * 64 + j], nqr = xb[4 * 64 + j], nqh = xb[5 * 64 + j];

    float h = 0.0f;
    const _Float16* prow = &s_h16[1][CH - 1][0];

#define XTRACT(DST, Q, TC)                                                    \
    {                                                                         \
        unsigned int _w = ((TC) >> 1) == 0 ? (Q).x : ((TC) >> 1) == 1 ?       \
            (Q).y : ((TC) >> 1) == 2 ? (Q).z : (Q).w;                         \
        if ((TC) & 1) _w >>= 16;                                              \
        DST = __half2float(__ushort_as_half((unsigned short)_w));             \
    }
// one b128 word (4 h-pairs) against weight pairs 4*QI..4*QI+3
#define CONS(QI, QV)                                                          \
    {                                                                         \
        const unsigned int* _u = (const unsigned int*)&(QV);                  \
        _Pragma("unroll")                                                     \
        for (int _w = 0; _w < 4; ++_w) {                                      \
            const h2v hp_ = u2h(_u[_w]);                                      \
            az = fdot2f(Pz[4 * (QI) + _w], hp_, az);                          \
            ar = fdot2f(Pr[4 * (QI) + _w], hp_, ar);                          \
            ah = fdot2f(Ph[4 * (QI) + _w], hp_, ah);                          \
        }                                                                     \
    }

#define STEP(TC)                                                              \
    {                                                                         \
        float xz, xr, xh;                                                     \
        XTRACT(xz, xqz, TC) XTRACT(xr, xqr, TC) XTRACT(xh, xqh, TC)           \
        const float4* hp4 = (const float4*)prow;                              \
        float az = 0.f, ar = 0.f, ah = 0.f;                                   \
        float4 q0 = hp4[0], q1 = hp4[1];                                      \
        CONS(0, q0) q0 = hp4[2];                                              \
        CONS(1, q1) q1 = hp4[3];                                              \
        CONS(2, q0) q0 = hp4[4];                                              \
        CONS(3, q1) q1 = hp4[5];                                              \
        CONS(4, q0) q0 = hp4[6];                                              \
        CONS(5, q1) q1 = hp4[7];                                              \
        CONS(6, q0)                                                           \
        CONS(7, q1)                                                           \
        const float z  = sigmoid_f(xz + az);                                  \
        const float r  = sigmoid_f(xr + ar);                                  \
        const float cc = tanh_f(xh + r * (bh + ah));                          \
        const float hn = z * h + (1.0f - z) * cc;                             \
        h = ((k * CH + (TC)) < len) ? hn : h;                                 \
        s_h16[cb][TC][j] = (_Float16)h;                                       \
        prow = &s_h16[cb][TC][0];                                             \
    }

#define HEAD(HB, TB)                                                          \
    {                                                                         \
        const int e = j & 7, s = j >> 3;                                      \
        float4 hw = *(const float4*)&s_h16[HB][s][e * 8];                     \
        const h2v* hp_ = (const h2v*)&hw;                                     \
        const float4* dr = (const float4*)&s_dw[e * 8];                       \
        float4 d0 = dr[0], d1 = dr[1];                                        \
        float pp = (float)hp_[0].x * d0.x + (float)hp_[0].y * d0.y            \
                 + (float)hp_[1].x * d0.z + (float)hp_[1].y * d0.w            \
                 + (float)hp_[2].x * d1.x + (float)hp_[2].y * d1.y            \
                 + (float)hp_[3].x * d1.z + (float)hp_[3].y * d1.w;           \
        pp += __shfl_xor(pp, 1, 64);                                          \
        pp += __shfl_xor(pp, 2, 64);                                          \
        pp += __shfl_xor(pp, 4, 64);                                          \
        if (e == 0) ob[(TB) + s] = sigmoid_f(pp + dbv);                       \
    }

#pragma unroll 1
    for (int k = 0; k < NCK; ++k) {
        const int cb = k & 1;
        if (k > 0) HEAD(cb ^ 1, (k - 1) * CH)
        STEP(0) STEP(1) STEP(2) STEP(3)
        STEP(4) STEP(5) STEP(6) STEP(7)
        if (k + 1 < NCK) {
            xqz = nqz; xqr = nqr; xqh = nqh;
            if (k + 2 < NCK) {
                const int kb = (k + 2) * 3;
                nqz = xb[(kb + 0) * 64 + j];
                nqr = xb[(kb + 1) * 64 + j];
                nqh = xb[(kb + 2) * 64 + j];
            }
        }
    }
    HEAD((NCK - 1) & 1, (NCK - 1) * CH)

#undef XTRACT
#undef CONS
#undef STEP
#undef HEAD
}

// =======================================================================
// Fallback (ws too small): R15's 2-wave kernel (486us, absmax 0).
// =======================================================================
__global__ __launch_bounds__(128)
__attribute__((amdgpu_waves_per_eu(1, 1)))
void gru_ldsb(const float* __restrict__ values, const int* __restrict__ lengths,
              const float* __restrict__ Wk, const float* __restrict__ Wr,
              const float* __restrict__ bias, const float* __restrict__ dw,
              const float* __restrict__ db, float* __restrict__ out)
{
    const int tid = threadIdx.x;
    const int j   = tid & 63;
    const int w   = tid >> 6;
    const int b   = blockIdx.x;
    __shared__ __align__(16) float s_v[2][CH][40];
    __shared__ float s_xp[2][CH][G3];
    __shared__ __align__(16) float s_h8[2][CH][76];
    const float* vbp = values + (size_t)b * TQ * FQ;
    float* ob = out + (size_t)b * TQ;
    if (w == 0) {
        v2f Pz[32], Pr[32], Ph[32];
#pragma unroll
        for (int i = 0; i < 32; ++i) {
            v2f tz, tr, th;
            tz.x = Wr[(2 * i) * G3 + j];        tz.y = Wr[(2 * i + 1) * G3 + j];
            tr.x = Wr[(2 * i) * G3 + 64 + j];   tr.y = Wr[(2 * i + 1) * G3 + 64 + j];
            th.x = Wr[(2 * i) * G3 + 128 + j];  th.y = Wr[(2 * i + 1) * G3 + 128 + j];
            Pz[i] = tz; Pr[i] = tr; Ph[i] = th;
        }
        const float bh = bias[G3 + 128 + j];
        const int len = lengths[b];
        s_h8[1][7][j] = 0.0f;
        asm volatile("s_waitcnt lgkmcnt(0)" ::: "memory");
        __builtin_amdgcn_s_barrier();
        float h = 0.0f;
        const float* hprev = &s_h8[1][7][0];
#pragma unroll 1
        for (int k = 0; k < NCK; ++k) {
            const int pb = k & 1;
            const int tbase = k * CH;
#pragma unroll 1
            for (int tc = 0; tc < CH; ++tc) {
                const float xz = s_xp[pb][tc][j];
                const float xr = s_xp[pb][tc][64 + j];
                const float xh = s_xp[pb][tc][128 + j];
                const float4* hp4 = (const float4*)hprev;
                v2f azp; azp.x = 0.f; azp.y = 0.f;
                v2f arp; arp.x = 0.f; arp.y = 0.f;
                v2f ahp; ahp.x = 0.f; ahp.y = 0.f;
#define PKB(ACC, WP, HV) asm("v_pk_fma_f32 %0, %1, %2, %0" \
        : "+v"(ACC) : "v"(WP), "v"(HV));
                float4 ha[8];
#pragma unroll
                for (int q = 0; q < 8; ++q) ha[q] = hp4[q];
#pragma unroll
                for (int q = 0; q < 8; ++q) {
                    const v2f* hv = (const v2f*)&ha[q];
                    PKB(azp, Pz[2 * q],     hv[0])
                    PKB(arp, Pr[2 * q],     hv[0])
                    PKB(ahp, Ph[2 * q],     hv[0])
                    PKB(azp, Pz[2 * q + 1], hv[1])
                    PKB(arp, Pr[2 * q + 1], hv[1])
                    PKB(ahp, Ph[2 * q + 1], hv[1])
                    ha[q] = hp4[8 + q];
                }
#pragma unroll
                for (int q = 0; q < 8; ++q) {
                    const v2f* hv = (const v2f*)&ha[q];
                    PKB(azp, Pz[16 + 2 * q],     hv[0])
                    PKB(arp, Pr[16 + 2 * q],     hv[0])
                    PKB(ahp, Ph[16 + 2 * q],     hv[0])
                    PKB(azp, Pz[16 + 2 * q + 1], hv[1])
                    PKB(arp, Pr[16 + 2 * q + 1], hv[1])
                    PKB(ahp, Ph[16 + 2 * q + 1], hv[1])
                }
#undef PKB
                const float az = azp.x + azp.y;
                const float ar = arp.x + arp.y;
                const float ah = ahp.x + ahp.y;
                const float z  = sigmoid_f(xz + az);
                const float r  = sigmoid_f(xr + ar);
                const float cc = tanh_f(xh + r * (bh + ah));
                const float hn = z * h + (1.0f - z) * cc;
                h = ((tbase + tc) < len) ? hn : h;
                s_h8[pb][tc][j] = h;
                asm volatile("s_waitcnt lgkmcnt(0)" ::: "memory");
                hprev = &s_h8[pb][tc][0];
            }
            __builtin_amdgcn_s_barrier();
        }
    } else {
        float Kz[FQ], Kr[FQ], Kh[FQ];
#pragma unroll
        for (int f = 0; f < FQ; ++f) {
            Kz[f] = Wk[f * G3 + j];
            Kr[f] = Wk[f * G3 + 64 + j];
            Kh[f] = Wk[f * G3 + 128 + j];
        }
        const float bz  = bias[j] + bias[G3 + j];
        const float br  = bias[64 + j] + bias[G3 + 64 + j];
        const float bhx = bias[128 + j];
        const float dbv = db[0];
        float dwv[8];
#pragma unroll
        for (int i = 0; i < 8; ++i) dwv[i] = dw[(j & 7) * 8 + i];
        int rq[5], cq[5];
        bool act[5];
        float stg[5];
#pragma unroll
        for (int q = 0; q < 5; ++q) {
            const int idx = j + 64 * q;
            act[q] = idx < CFD;
            rq[q] = idx / FQ;
            cq[q] = idx - rq[q] * FQ;
            stg[q] = 0.0f;
        }
#define STAGE_LOAD(CK)                                                        \
        _Pragma("unroll")                                                     \
        for (int q = 0; q < 5; ++q)                                           \
            if (act[q]) stg[q] = vbp[(size_t)(CK) * CFD + j + 64 * q];
#define STAGE_WRITE(SB)                                                       \
        _Pragma("unroll")                                                     \
        for (int q = 0; q < 5; ++q)                                           \
            if (act[q]) s_v[SB][rq[q]][cq[q]] = stg[q];
#define XF(VAL, I) { az += (VAL) * Kz[I]; ar += (VAL) * Kr[I]; ah += (VAL) * Kh[I]; }
#define XPROW(BB)                                                             \
    _Pragma("unroll 1")                                                       \
    for (int row = 0; row < CH; ++row) {                                      \
        const float4* vr = (const float4*)&s_v[BB][row][0];                   \
        float az = bz, ar = br, ah = bhx;                                     \
        { float4 v0 = vr[0], v1 = vr[1], v2 = vr[2];                          \
          XF(v0.x, 0)  XF(v0.y, 1)  XF(v0.z, 2)  XF(v0.w, 3)                  \
          XF(v1.x, 4)  XF(v1.y, 5)  XF(v1.z, 6)  XF(v1.w, 7)                  \
          XF(v2.x, 8)  XF(v2.y, 9)  XF(v2.z, 10) XF(v2.w, 11) }               \
        { float4 v3 = vr[3], v4 = vr[4], v5 = vr[5];                          \
          XF(v3.x, 12) XF(v3.y, 13) XF(v3.z, 14) XF(v3.w, 15)                 \
          XF(v4.x, 16) XF(v4.y, 17) XF(v4.z, 18) XF(v4.w, 19)                 \
          XF(v5.x, 20) XF(v5.y, 21) XF(v5.z, 22) XF(v5.w, 23) }               \
        { float4 v6 = vr[6], v7 = vr[7], v8 = vr[8];                          \
          float f36 = s_v[BB][row][36];                                       \
          XF(v6.x, 24) XF(v6.y, 25) XF(v6.z, 26) XF(v6.w, 27)                 \
          XF(v7.x, 28) XF(v7.y, 29) XF(v7.z, 30) XF(v7.w, 31)                 \
          XF(v8.x, 32) XF(v8.y, 33) XF(v8.z, 34) XF(v8.w, 35)                 \
          XF(f36, 36) }                                                       \
        s_xp[BB][row][j]       = az;                                          \
        s_xp[BB][row][64 + j]  = ar;                                          \
        s_xp[BB][row][128 + j] = ah;                                          \
    }
#define HEADF(HB, TB)                                                         \
    {                                                                         \
        const int e = j & 7, s = j >> 3;                                      \
        const float4* hr = (const float4*)&s_h8[HB][s][e * 8];                \
        float4 ha = hr[0], hc = hr[1];                                        \
        float pp = ha.x * dwv[0] + ha.y * dwv[1] + ha.z * dwv[2]              \
                 + ha.w * dwv[3] + hc.x * dwv[4] + hc.y * dwv[5]              \
                 + hc.z * dwv[6] + hc.w * dwv[7];                             \
        pp += __shfl_xor(pp, 1, 64);                                          \
        pp += __shfl_xor(pp, 2, 64);                                          \
        pp += __shfl_xor(pp, 4, 64);                                          \
        if (e == 0) ob[(TB) + s] = sigmoid_f(pp + dbv);                       \
    }
        STAGE_LOAD(0)
        asm volatile("s_waitcnt vmcnt(0)" ::: "memory");
        STAGE_WRITE(0)
        STAGE_LOAD(1)
        asm volatile("s_waitcnt vmcnt(0)" ::: "memory");
        STAGE_WRITE(1)
        STAGE_LOAD(2)
        asm volatile("s_waitcnt lgkmcnt(0)" ::: "memory");
        XPROW(0)
        asm volatile("s_waitcnt lgkmcnt(0)" ::: "memory");
        __builtin_amdgcn_s_barrier();
#pragma unroll 1
        for (int k = 0; k < NCK; ++k) {
            const int pb = k & 1, nb = pb ^ 1;
            if (k > 0) HEADF(nb, (k - 1) * CH)
            if (k + 2 < NCK) {
                asm volatile("s_waitcnt vmcnt(0)" ::: "memory");
                STAGE_WRITE(pb)
                if (k + 3 < NCK) STAGE_LOAD(k + 3)
            }
            if (k + 1 < NCK) XPROW(nb)
            asm volatile("s_waitcnt lgkmcnt(0)" ::: "memory");
            __builtin_amdgcn_s_barrier();
        }
        HEADF((NCK - 1) & 1, (NCK - 1) * CH)
#undef STAGE_LOAD
#undef STAGE_WRITE
#undef XF
#undef XPROW
#undef HEADF
    }
}

extern "C" void kernel_launch(void* const* d_in, const int* in_sizes, int n_in,
                              void* d_out, int out_size, void* d_ws, size_t ws_size,
                              hipStream_t stream) {
    const float* values  = (const float*)d_in[2];
    const int*   lengths = (const int*)  d_in[4];
    const float* Wk      = (const float*)d_in[5];
    const float* Wr      = (const float*)d_in[6];
    const float* bias    = (const float*)d_in[7];
    const float* dw      = (const float*)d_in[8];
    const float* db      = (const float*)d_in[9];
    float* out = (float*)d_out;

    const size_t need = (size_t)BQ * TQ * G3 * sizeof(__half);  // 100.66 MB
    if (ws_size >= need) {
        __half* xp = (__half*)d_ws;
        xp_kernel<<<dim3(BQ * 16), dim3(64), 0, stream>>>(values, Wk, bias, xp);
        gru_1w<<<dim3(BQ), dim3(64), 0, stream>>>(
            lengths, Wr, bias, dw, db, xp, out);
    } else {
        gru_ldsb<<<dim3(BQ), dim3(128), 0, stream>>>(
            values, lengths, Wk, Wr, bias, dw, db, out);
    }
}

// Round 19
// 383.540 us; speedup vs baseline: 1.6567x; 1.4216x over previous
//
#include <hip/hip_runtime.h>
#include <hip/hip_fp16.h>

#define BQ 256
#define TQ 1024
#define FQ 37
#define UQ 64
#define G3 192
#define CH 8
#define NCK (TQ / CH)
#define CFD (CH * FQ)   // 296 dwords per staged chunk

typedef _Float16 h2v __attribute__((ext_vector_type(2)));

__device__ __forceinline__ float sigmoid_f(float x) {
    return 1.0f / (1.0f + __expf(-x));
}
__device__ __forceinline__ float tanh_f(float x) {
    return 1.0f - 2.0f / (__expf(2.0f * x) + 1.0f);
}
__device__ __forceinline__ float fdot2f(h2v a, h2v b, float c) {
#if __has_builtin(__builtin_amdgcn_fdot2)
    return __builtin_amdgcn_fdot2(a, b, c, false);
#else
    float d;
    asm("v_dot2_f32_f16 %0, %1, %2, %3" : "=v"(d) : "v"(a), "v"(b), "v"(c));
    return d;
#endif
}

// 2 waves / block, producer/consumer, DISJOINT per-role loops (R10 structure,
// proven absmax 0) + fp16 consumer (R18, proven absmax 0.0039):
//  - fp16 weights shrink the consumer branch to ~150 VGPR, so BOTH branches
//    fit far under the 256 arch cap: the pressure disease (R9-R17: AGPR
//    parking / remat / spill) is gone by construction. No ws, one launch.
//  - R18's residual stall fixed: h-broadcast reads go into 8 DISTINCT float4
//    regs (R18 rotated 2 regs -> WAR hazards serialized the reads into ~4
//    dependent 120cy LDS-latency waves), and each gate uses 2 accumulators
//    (chain depth 32 -> 16, below the 96-fdot2 issue floor).
//  wave0 consumer: lane j owns h_j + gate cols j/64+j/128+j; per step:
//    lgkm-drain, 8 uniform ds_read_b128 (fp16 h) + 3 xp b32, 96 fdot2,
//    gates, ds_write_b16 h. No barriers inside a chunk.
//  wave1 producer: stages values 2 chunks ahead, fp32 xp 1 chunk ahead into
//    LDS, dense head 1 chunk behind (reads fp16 h ring). Barrier per chunk.
__global__ __launch_bounds__(128)
__attribute__((amdgpu_waves_per_eu(1, 1)))
void gru_fused(const float* __restrict__ values,   // [B,T,F]
               const int*   __restrict__ lengths,  // [B]
               const float* __restrict__ Wk,       // [F,3U]
               const float* __restrict__ Wr,       // [U,3U]
               const float* __restrict__ bias,     // [2,3U]
               const float* __restrict__ dw,       // [U]
               const float* __restrict__ db,       // [1]
               float*       __restrict__ out)      // [B,T]
{
    const int tid = threadIdx.x;
    const int j   = tid & 63;
    const int w   = tid >> 6;
    const int b   = blockIdx.x;

    __shared__ __align__(16) float    s_v[2][CH][40];    // staged values (dbuf)
    __shared__ float                  s_xp[2][CH][G3];   // x-projections (dbuf)
    __shared__ __align__(16) _Float16 s_h16[2][CH][72];  // h ring, fp16 (144B rows)

    const float* vbp = values + (size_t)b * TQ * FQ;
    float* ob = out + (size_t)b * TQ;

    if (w == 0) {
        // ================= CONSUMER =================
        h2v Pz[32], Pr[32], Ph[32];          // fp16 weight pairs (96 VGPRs)
#pragma unroll
        for (int i = 0; i < 32; ++i) {
            h2v tz, tr, th;
            tz.x = (_Float16)Wr[(2 * i) * G3 + j];
            tz.y = (_Float16)Wr[(2 * i + 1) * G3 + j];
            tr.x = (_Float16)Wr[(2 * i) * G3 + 64 + j];
            tr.y = (_Float16)Wr[(2 * i + 1) * G3 + 64 + j];
            th.x = (_Float16)Wr[(2 * i) * G3 + 128 + j];
            th.y = (_Float16)Wr[(2 * i + 1) * G3 + 128 + j];
            Pz[i] = tz; Pr[i] = tr; Ph[i] = th;
        }
        const float bh  = bias[G3 + 128 + j];    // h-gate recurrent bias
        const int   len = lengths[b];

        s_h16[1][CH - 1][j] = (_Float16)0.0f;    // h0 = 0 slot
        asm volatile("s_waitcnt lgkmcnt(0)" ::: "memory");
        __builtin_amdgcn_s_barrier();            // prologue barrier

        float h = 0.0f;                          // lane j holds h_j
        const _Float16* prow = &s_h16[1][CH - 1][0];

// one b128 word (4 h2v pairs) against weight pairs 4*QI..4*QI+3;
// even pair -> acc0, odd pair -> acc1 (chain depth 16 per accumulator)
#define CONSH(QI, QV)                                                         \
        {                                                                     \
            const h2v* hv = (const h2v*)&(QV);                                \
            az0 = fdot2f(Pz[4 * (QI) + 0], hv[0], az0);                       \
            az1 = fdot2f(Pz[4 * (QI) + 1], hv[1], az1);                       \
            ar0 = fdot2f(Pr[4 * (QI) + 0], hv[0], ar0);                       \
            ar1 = fdot2f(Pr[4 * (QI) + 1], hv[1], ar1);                       \
            ah0 = fdot2f(Ph[4 * (QI) + 0], hv[0], ah0);                       \
            ah1 = fdot2f(Ph[4 * (QI) + 1], hv[1], ah1);                       \
            az0 = fdot2f(Pz[4 * (QI) + 2], hv[2], az0);                       \
            az1 = fdot2f(Pz[4 * (QI) + 3], hv[3], az1);                       \
            ar0 = fdot2f(Pr[4 * (QI) + 2], hv[2], ar0);                       \
            ar1 = fdot2f(Pr[4 * (QI) + 3], hv[3], ar1);                       \
            ah0 = fdot2f(Ph[4 * (QI) + 2], hv[2], ah0);                       \
            ah1 = fdot2f(Ph[4 * (QI) + 3], hv[3], ah1);                       \
        }

#define CSTEP(TC)                                                             \
        {                                                                     \
            asm volatile("s_waitcnt lgkmcnt(0)" ::: "memory"); /* h-write */  \
            const float4* hp4 = (const float4*)prow;                          \
            float4 q0 = hp4[0], q1 = hp4[1], q2 = hp4[2], q3 = hp4[3],        \
                   q4 = hp4[4], q5 = hp4[5], q6 = hp4[6], q7 = hp4[7];        \
            const float xz = s_xp[pb][TC][j];                                 \
            const float xr = s_xp[pb][TC][64 + j];                            \
            const float xh = s_xp[pb][TC][128 + j];                           \
            float az0 = 0.f, az1 = 0.f, ar0 = 0.f, ar1 = 0.f,                 \
                  ah0 = 0.f, ah1 = 0.f;                                       \
            CONSH(0, q0) CONSH(1, q1) CONSH(2, q2) CONSH(3, q3)               \
            CONSH(4, q4) CONSH(5, q5) CONSH(6, q6) CONSH(7, q7)               \
            const float z  = sigmoid_f(xz + (az0 + az1));                     \
            const float r  = sigmoid_f(xr + (ar0 + ar1));                     \
            const float cc = tanh_f(xh + r * (bh + (ah0 + ah1)));             \
            const float hn = z * h + (1.0f - z) * cc;                         \
            h = ((tbase + (TC)) < len) ? hn : h;                              \
            s_h16[pb][TC][j] = (_Float16)h;                                   \
            prow = &s_h16[pb][TC][0];                                         \
        }

#pragma unroll 1
        for (int k = 0; k < NCK; ++k) {
            const int pb = k & 1;
            const int tbase = k * CH;
            CSTEP(0) CSTEP(1) CSTEP(2) CSTEP(3)
            CSTEP(4) CSTEP(5) CSTEP(6) CSTEP(7)
            asm volatile("s_waitcnt lgkmcnt(0)" ::: "memory");
            __builtin_amdgcn_s_barrier();        // once per 8 steps
        }
#undef CSTEP
#undef CONSH
    } else {
        // ================= PRODUCER (R10 verbatim; head reads fp16 h) =====
        float Kz[FQ], Kr[FQ], Kh[FQ];
#pragma unroll
        for (int f = 0; f < FQ; ++f) {
            Kz[f] = Wk[f * G3 + j];
            Kr[f] = Wk[f * G3 + 64 + j];
            Kh[f] = Wk[f * G3 + 128 + j];
        }
        const float bz  = bias[j] + bias[G3 + j];            // fold rec bias z
        const float br  = bias[64 + j] + bias[G3 + 64 + j];  // fold rec bias r
        const float bhx = bias[128 + j];                     // input bias only
        const float dbv = db[0];
        float dwv[8];
#pragma unroll
        for (int i = 0; i < 8; ++i) dwv[i] = dw[(j & 7) * 8 + i];

        int rq[5], cq[5];
        bool act[5];
        float stg[5];
#pragma unroll
        for (int q = 0; q < 5; ++q) {
            const int idx = j + 64 * q;
            act[q] = idx < CFD;
            rq[q] = idx / FQ;
            cq[q] = idx - rq[q] * FQ;
            stg[q] = 0.0f;
        }

#define STAGE_LOAD(CK)                                                        \
        _Pragma("unroll")                                                     \
        for (int q = 0; q < 5; ++q)                                           \
            if (act[q]) stg[q] = vbp[(size_t)(CK) * CFD + j + 64 * q];
#define STAGE_WRITE(SB)                                                       \
        _Pragma("unroll")                                                     \
        for (int q = 0; q < 5; ++q)                                           \
            if (act[q]) s_v[SB][rq[q]][cq[q]] = stg[q];

#define XF(VAL, I) { az += (VAL) * Kz[I]; ar += (VAL) * Kr[I]; ah += (VAL) * Kh[I]; }
#define XPROW(BB)                                                             \
    _Pragma("unroll 1")                                                       \
    for (int row = 0; row < CH; ++row) {                                      \
        const float4* vr = (const float4*)&s_v[BB][row][0];                   \
        float az = bz, ar = br, ah = bhx;                                     \
        { float4 v0 = vr[0], v1 = vr[1], v2 = vr[2];                          \
          XF(v0.x, 0)  XF(v0.y, 1)  XF(v0.z, 2)  XF(v0.w, 3)                  \
          XF(v1.x, 4)  XF(v1.y, 5)  XF(v1.z, 6)  XF(v1.w, 7)                  \
          XF(v2.x, 8)  XF(v2.y, 9)  XF(v2.z, 10) XF(v2.w, 11) }               \
        { float4 v3 = vr[3], v4 = vr[4], v5 = vr[5];                          \
          XF(v3.x, 12) XF(v3.y, 13) XF(v3.z, 14) XF(v3.w, 15)                 \
          XF(v4.x, 16) XF(v4.y, 17) XF(v4.z, 18) XF(v4.w, 19)                 \
          XF(v5.x, 20) XF(v5.y, 21) XF(v5.z, 22) XF(v5.w, 23) }               \
        { float4 v6 = vr[6], v7 = vr[7], v8 = vr[8];                          \
          float f36 = s_v[BB][row][36];                                       \
          XF(v6.x, 24) XF(v6.y, 25) XF(v6.z, 26) XF(v6.w, 27)                 \
          XF(v7.x, 28) XF(v7.y, 29) XF(v7.z, 30) XF(v7.w, 31)                 \
          XF(v8.x, 32) XF(v8.y, 33) XF(v8.z, 34) XF(v8.w, 35)                 \
          XF(f36, 36) }                                                       \
        s_xp[BB][row][j]       = az;                                          \
        s_xp[BB][row][64 + j]  = ar;                                          \
        s_xp[BB][row][128 + j] = ah;                                          \
    }

#define HEAD(HB, TB)                                                          \
    {                                                                         \
        const int e = j & 7, s = j >> 3;                                      \
        float4 hw = *(const float4*)&s_h16[HB][s][e * 8];                     \
        const h2v* hp_ = (const h2v*)&hw;                                     \
        float pp = (float)hp_[0].x * dwv[0] + (float)hp_[0].y * dwv[1]        \
                 + (float)hp_[1].x * dwv[2] + (float)hp_[1].y * dwv[3]        \
                 + (float)hp_[2].x * dwv[4] + (float)hp_[2].y * dwv[5]        \
                 + (float)hp_[3].x * dwv[6] + (float)hp_[3].y * dwv[7];       \
        pp += __shfl_xor(pp, 1, 64);                                          \
        pp += __shfl_xor(pp, 2, 64);                                          \
        pp += __shfl_xor(pp, 4, 64);                                          \
        if (e == 0) ob[(TB) + s] = sigmoid_f(pp + dbv);                       \
    }

        // prologue: chunk0 -> s_v[0]; chunk1 -> s_v[1]; issue chunk2; xp(chunk0)
        STAGE_LOAD(0)
        asm volatile("s_waitcnt vmcnt(0)" ::: "memory");
        STAGE_WRITE(0)
        STAGE_LOAD(1)
        asm volatile("s_waitcnt vmcnt(0)" ::: "memory");
        STAGE_WRITE(1)
        STAGE_LOAD(2)
        asm volatile("s_waitcnt lgkmcnt(0)" ::: "memory");  // own s_v visible
        XPROW(0)
        asm volatile("s_waitcnt lgkmcnt(0)" ::: "memory");
        __builtin_amdgcn_s_barrier();            // prologue barrier

#pragma unroll 1
        for (int k = 0; k < NCK; ++k) {
            const int pb = k & 1, nb = pb ^ 1;
            if (k > 0) HEAD(nb, (k - 1) * CH)
            if (k + 2 < NCK) {
                asm volatile("s_waitcnt vmcnt(0)" ::: "memory");
                STAGE_WRITE(pb)                  // chunk k+2
                if (k + 3 < NCK) STAGE_LOAD(k + 3)
            }
            if (k + 1 < NCK) XPROW(nb)           // xp chunk k+1 from s_v[nb]
            asm volatile("s_waitcnt lgkmcnt(0)" ::: "memory");
            __builtin_amdgcn_s_barrier();        // once per 8 steps
        }
        HEAD((NCK - 1) & 1, (NCK - 1) * CH)      // after final barrier (R13 fix)

#undef STAGE_LOAD
#undef STAGE_WRITE
#undef XF
#undef XPROW
#undef HEAD
    }
}

extern "C" void kernel_launch(void* const* d_in, const int* in_sizes, int n_in,
                              void* d_out, int out_size, void* d_ws, size_t ws_size,
                              hipStream_t stream) {
    const float* values  = (const float*)d_in[2];
    const int*   lengths = (const int*)  d_in[4];
    const float* Wk      = (const float*)d_in[5];
    const float* Wr      = (const float*)d_in[6];
    const float* bias    = (const float*)d_in[7];
    const float* dw      = (const float*)d_in[8];
    const float* db      = (const float*)d_in[9];
    float* out = (float*)d_out;

    gru_fused<<<dim3(BQ), dim3(128), 0, stream>>>(
        values, lengths, Wk, Wr, bias, dw, db, out);
}

// Round 20
// 380.970 us; speedup vs baseline: 1.6679x; 1.0067x over previous
//
#include <hip/hip_runtime.h>
#include <hip/hip_fp16.h>

#define BQ 256
#define TQ 1024
#define FQ 37
#define UQ 64
#define G3 192
#define CH 8
#define NCK (TQ / CH)
#define CFD (CH * FQ)   // 296 dwords per staged chunk

typedef _Float16 h2v __attribute__((ext_vector_type(2)));

__device__ __forceinline__ float sigmoid_f(float x) {
    return 1.0f / (1.0f + __expf(-x));
}
__device__ __forceinline__ float tanh_f(float x) {
    return 1.0f - 2.0f / (__expf(2.0f * x) + 1.0f);
}
__device__ __forceinline__ float fdot2f(h2v a, h2v b, float c) {
#if __has_builtin(__builtin_amdgcn_fdot2)
    return __builtin_amdgcn_fdot2(a, b, c, false);
#else
    float d;
    asm("v_dot2_f32_f16 %0, %1, %2, %3" : "=v"(d) : "v"(a), "v"(b), "v"(c));
    return d;
#endif
}

// R19 (383us) + two latency cuts in the consumer step:
//  1. The per-step lgkmcnt(0) between the h ds_write and the broadcast reads
//     is REMOVED: the LDS pipe is in-order within a wave, so a read issued
//     after a write to the same address is serviced after it. Only compiler
//     reordering must be stopped -> sched_barrier(0) after the write (free).
//     Cross-wave visibility (producer HEAD) still guarded by the chunk-end
//     lgkmcnt(0)+barrier, unchanged.
//  2. xp packed as float4 {z,r,h,-} per (row,lane); all 8 steps' xp loads
//     issue at chunk start (32 VGPRs), latency hidden under step-0 broadcast.
// Numerics bit-identical to R19 (absmax 0.0039 expected unchanged).
__global__ __launch_bounds__(128)
__attribute__((amdgpu_waves_per_eu(1, 1)))
void gru_fused(const float* __restrict__ values,   // [B,T,F]
               const int*   __restrict__ lengths,  // [B]
               const float* __restrict__ Wk,       // [F,3U]
               const float* __restrict__ Wr,       // [U,3U]
               const float* __restrict__ bias,     // [2,3U]
               const float* __restrict__ dw,       // [U]
               const float* __restrict__ db,       // [1]
               float*       __restrict__ out)      // [B,T]
{
    const int tid = threadIdx.x;
    const int j   = tid & 63;
    const int w   = tid >> 6;
    const int b   = blockIdx.x;

    __shared__ __align__(16) float    s_v[2][CH][40];     // staged values (dbuf)
    __shared__ __align__(16) float4   s_xp4[2][CH][64];   // packed xp {z,r,h,-}
    __shared__ __align__(16) _Float16 s_h16[2][CH][72];   // h ring, fp16

    const float* vbp = values + (size_t)b * TQ * FQ;
    float* ob = out + (size_t)b * TQ;

    if (w == 0) {
        // ================= CONSUMER =================
        h2v Pz[32], Pr[32], Ph[32];          // fp16 weight pairs (96 VGPRs)
#pragma unroll
        for (int i = 0; i < 32; ++i) {
            h2v tz, tr, th;
            tz.x = (_Float16)Wr[(2 * i) * G3 + j];
            tz.y = (_Float16)Wr[(2 * i + 1) * G3 + j];
            tr.x = (_Float16)Wr[(2 * i) * G3 + 64 + j];
            tr.y = (_Float16)Wr[(2 * i + 1) * G3 + 64 + j];
            th.x = (_Float16)Wr[(2 * i) * G3 + 128 + j];
            th.y = (_Float16)Wr[(2 * i + 1) * G3 + 128 + j];
            Pz[i] = tz; Pr[i] = tr; Ph[i] = th;
        }
        const float bh  = bias[G3 + 128 + j];    // h-gate recurrent bias
        const int   len = lengths[b];

        s_h16[1][CH - 1][j] = (_Float16)0.0f;    // h0 = 0 slot
        asm volatile("s_waitcnt lgkmcnt(0)" ::: "memory");
        __builtin_amdgcn_s_barrier();            // prologue barrier

        float h = 0.0f;                          // lane j holds h_j
        const _Float16* prow = &s_h16[1][CH - 1][0];

#define CONSH(QI, QV)                                                         \
        {                                                                     \
            const h2v* hv = (const h2v*)&(QV);                                \
            az0 = fdot2f(Pz[4 * (QI) + 0], hv[0], az0);                       \
            az1 = fdot2f(Pz[4 * (QI) + 1], hv[1], az1);                       \
            ar0 = fdot2f(Pr[4 * (QI) + 0], hv[0], ar0);                       \
            ar1 = fdot2f(Pr[4 * (QI) + 1], hv[1], ar1);                       \
            ah0 = fdot2f(Ph[4 * (QI) + 0], hv[0], ah0);                       \
            ah1 = fdot2f(Ph[4 * (QI) + 1], hv[1], ah1);                       \
            az0 = fdot2f(Pz[4 * (QI) + 2], hv[2], az0);                       \
            az1 = fdot2f(Pz[4 * (QI) + 3], hv[3], az1);                       \
            ar0 = fdot2f(Pr[4 * (QI) + 2], hv[2], ar0);                       \
            ar1 = fdot2f(Pr[4 * (QI) + 3], hv[3], ar1);                       \
            ah0 = fdot2f(Ph[4 * (QI) + 2], hv[2], ah0);                       \
            ah1 = fdot2f(Ph[4 * (QI) + 3], hv[3], ah1);                       \
        }

#define CSTEP(TC, XQ)                                                         \
        {                                                                     \
            const float4* hp4 = (const float4*)prow;                          \
            float4 q0 = hp4[0], q1 = hp4[1], q2 = hp4[2], q3 = hp4[3],        \
                   q4 = hp4[4], q5 = hp4[5], q6 = hp4[6], q7 = hp4[7];        \
            float az0 = 0.f, az1 = 0.f, ar0 = 0.f, ar1 = 0.f,                 \
                  ah0 = 0.f, ah1 = 0.f;                                       \
            CONSH(0, q0) CONSH(1, q1) CONSH(2, q2) CONSH(3, q3)               \
            CONSH(4, q4) CONSH(5, q5) CONSH(6, q6) CONSH(7, q7)               \
            const float z  = sigmoid_f((XQ).x + (az0 + az1));                 \
            const float r  = sigmoid_f((XQ).y + (ar0 + ar1));                 \
            const float cc = tanh_f((XQ).z + r * (bh + (ah0 + ah1)));         \
            const float hn = z * h + (1.0f - z) * cc;                         \
            h = ((tbase + (TC)) < len) ? hn : h;                              \
            s_h16[pb][TC][j] = (_Float16)h;                                   \
            __builtin_amdgcn_sched_barrier(0);  /* pin write before reads */  \
            prow = &s_h16[pb][TC][0];                                         \
        }

#pragma unroll 1
        for (int k = 0; k < NCK; ++k) {
            const int pb = k & 1;
            const int tbase = k * CH;
            // all 8 steps' packed xp: issued up-front, latency hides
            const float4* xpr = &s_xp4[pb][0][j];
            float4 xq0 = xpr[0 * 64], xq1 = xpr[1 * 64];
            float4 xq2 = xpr[2 * 64], xq3 = xpr[3 * 64];
            float4 xq4 = xpr[4 * 64], xq5 = xpr[5 * 64];
            float4 xq6 = xpr[6 * 64], xq7 = xpr[7 * 64];
            CSTEP(0, xq0) CSTEP(1, xq1) CSTEP(2, xq2) CSTEP(3, xq3)
            CSTEP(4, xq4) CSTEP(5, xq5) CSTEP(6, xq6) CSTEP(7, xq7)
            asm volatile("s_waitcnt lgkmcnt(0)" ::: "memory");
            __builtin_amdgcn_s_barrier();        // once per 8 steps
        }
#undef CSTEP
#undef CONSH
    } else {
        // ================= PRODUCER (R19; xp now packed float4) ==========
        float Kz[FQ], Kr[FQ], Kh[FQ];
#pragma unroll
        for (int f = 0; f < FQ; ++f) {
            Kz[f] = Wk[f * G3 + j];
            Kr[f] = Wk[f * G3 + 64 + j];
            Kh[f] = Wk[f * G3 + 128 + j];
        }
        const float bz  = bias[j] + bias[G3 + j];            // fold rec bias z
        const float br  = bias[64 + j] + bias[G3 + 64 + j];  // fold rec bias r
        const float bhx = bias[128 + j];                     // input bias only
        const float dbv = db[0];
        float dwv[8];
#pragma unroll
        for (int i = 0; i < 8; ++i) dwv[i] = dw[(j & 7) * 8 + i];

        int rq[5], cq[5];
        bool act[5];
        float stg[5];
#pragma unroll
        for (int q = 0; q < 5; ++q) {
            const int idx = j + 64 * q;
            act[q] = idx < CFD;
            rq[q] = idx / FQ;
            cq[q] = idx - rq[q] * FQ;
            stg[q] = 0.0f;
        }

#define STAGE_LOAD(CK)                                                        \
        _Pragma("unroll")                                                     \
        for (int q = 0; q < 5; ++q)                                           \
            if (act[q]) stg[q] = vbp[(size_t)(CK) * CFD + j + 64 * q];
#define STAGE_WRITE(SB)                                                       \
        _Pragma("unroll")                                                     \
        for (int q = 0; q < 5; ++q)                                           \
            if (act[q]) s_v[SB][rq[q]][cq[q]] = stg[q];

#define XF(VAL, I) { az += (VAL) * Kz[I]; ar += (VAL) * Kr[I]; ah += (VAL) * Kh[I]; }
#define XPROW(BB)                                                             \
    _Pragma("unroll 1")                                                       \
    for (int row = 0; row < CH; ++row) {                                      \
        const float4* vr = (const float4*)&s_v[BB][row][0];                   \
        float az = bz, ar = br, ah = bhx;                                     \
        { float4 v0 = vr[0], v1 = vr[1], v2 = vr[2];                          \
          XF(v0.x, 0)  XF(v0.y, 1)  XF(v0.z, 2)  XF(v0.w, 3)                  \
          XF(v1.x, 4)  XF(v1.y, 5)  XF(v1.z, 6)  XF(v1.w, 7)                  \
          XF(v2.x, 8)  XF(v2.y, 9)  XF(v2.z, 10) XF(v2.w, 11) }               \
        { float4 v3 = vr[3], v4 = vr[4], v5 = vr[5];                          \
          XF(v3.x, 12) XF(v3.y, 13) XF(v3.z, 14) XF(v3.w, 15)                 \
          XF(v4.x, 16) XF(v4.y, 17) XF(v4.z, 18) XF(v4.w, 19)                 \
          XF(v5.x, 20) XF(v5.y, 21) XF(v5.z, 22) XF(v5.w, 23) }               \
        { float4 v6 = vr[6], v7 = vr[7], v8 = vr[8];                          \
          float f36 = s_v[BB][row][36];                                       \
          XF(v6.x, 24) XF(v6.y, 25) XF(v6.z, 26) XF(v6.w, 27)                 \
          XF(v7.x, 28) XF(v7.y, 29) XF(v7.z, 30) XF(v7.w, 31)                 \
          XF(v8.x, 32) XF(v8.y, 33) XF(v8.z, 34) XF(v8.w, 35)                 \
          XF(f36, 36) }                                                       \
        float4 xo; xo.x = az; xo.y = ar; xo.z = ah; xo.w = 0.f;               \
        s_xp4[BB][row][j] = xo;                                               \
    }

#define HEAD(HB, TB)                                                          \
    {                                                                         \
        const int e = j & 7, s = j >> 3;                                      \
        float4 hw = *(const float4*)&s_h16[HB][s][e * 8];                     \
        const h2v* hp_ = (const h2v*)&hw;                                     \
        float pp = (float)hp_[0].x * dwv[0] + (float)hp_[0].y * dwv[1]        \
                 + (float)hp_[1].x * dwv[2] + (float)hp_[1].y * dwv[3]        \
                 + (float)hp_[2].x * dwv[4] + (float)hp_[2].y * dwv[5]        \
                 + (float)hp_[3].x * dwv[6] + (float)hp_[3].y * dwv[7];       \
        pp += __shfl_xor(pp, 1, 64);                                          \
        pp += __shfl_xor(pp, 2, 64);                                          \
        pp += __shfl_xor(pp, 4, 64);                                          \
        if (e == 0) ob[(TB) + s] = sigmoid_f(pp + dbv);                       \
    }

        // prologue: chunk0 -> s_v[0]; chunk1 -> s_v[1]; issue chunk2; xp(chunk0)
        STAGE_LOAD(0)
        asm volatile("s_waitcnt vmcnt(0)" ::: "memory");
        STAGE_WRITE(0)
        STAGE_LOAD(1)
        asm volatile("s_waitcnt vmcnt(0)" ::: "memory");
        STAGE_WRITE(1)
        STAGE_LOAD(2)
        asm volatile("s_waitcnt lgkmcnt(0)" ::: "memory");  // own s_v visible
        XPROW(0)
        asm volatile("s_waitcnt lgkmcnt(0)" ::: "memory");
        __builtin_amdgcn_s_barrier();            // prologue barrier

#pragma unroll 1
        for (int k = 0; k < NCK; ++k) {
            const int pb = k & 1, nb = pb ^ 1;
            if (k > 0) HEAD(nb, (k - 1) * CH)
            if (k + 2 < NCK) {
                asm volatile("s_waitcnt vmcnt(0)" ::: "memory");
                STAGE_WRITE(pb)                  // chunk k+2
                if (k + 3 < NCK) STAGE_LOAD(k + 3)
            }
            if (k + 1 < NCK) XPROW(nb)           // xp chunk k+1 from s_v[nb]
            asm volatile("s_waitcnt lgkmcnt(0)" ::: "memory");
            __builtin_amdgcn_s_barrier();        // once per 8 steps
        }
        HEAD((NCK - 1) & 1, (NCK - 1) * CH)      // after final barrier (R13 fix)

#undef STAGE_LOAD
#undef STAGE_WRITE
#undef XF
#undef XPROW
#undef HEAD
    }
}

extern "C" void kernel_launch(void* const* d_in, const int* in_sizes, int n_in,
                              void* d_out, int out_size, void* d_ws, size_t ws_size,
                              hipStream_t stream) {
    const float* values  = (const float*)d_in[2];
    const int*   lengths = (const int*)  d_in[4];
    const float* Wk      = (const float*)d_in[5];
    const float* Wr      = (const float*)d_in[6];
    const float* bias    = (const float*)d_in[7];
    const float* dw      = (const float*)d_in[8];
    const float* db      = (const float*)d_in[9];
    float* out = (float*)d_out;

    gru_fused<<<dim3(BQ), dim3(128), 0, stream>>>(
        values, lengths, Wk, Wr, bias, dw, db, out);
}